// Round 10
// baseline (408.260 us; speedup 1.0000x reference)
//
#include <hip/hip_runtime.h>
#include <hip/hip_bf16.h>
#include <cstdint>

#define N 4096
#define DIM 128
#define WEIGHT 0.01f
#define EPSQ 1e-12f
#define MAXKEY 0xFFFFFFFFFFFFFFFFull

#define RBLOCKS 512
#define RTHREADS 256
#define QPT (N / RTHREADS)  // 16 components per thread in merge

typedef unsigned long long u64;
typedef unsigned int u32;
typedef unsigned short u16;
typedef short short8 __attribute__((ext_vector_type(8)));
typedef u16 us8 __attribute__((ext_vector_type(8)));
typedef float f32x4 __attribute__((ext_vector_type(4)));

__device__ __forceinline__ u16 f32_to_bf16(float f) {
    const unsigned u = __float_as_uint(f);
    return (u16)((u + 0x7FFFu + ((u >> 16) & 1u)) >> 16);  // round-to-nearest-even
}

// ---- K1: fused prep: xb = bf16(x), sq = ||x_i||^2, + Boruvka state init ----
__global__ void prep_kernel(const float* __restrict__ x, u16* __restrict__ xb,
                            float* __restrict__ sq, u16* __restrict__ comp,
                            u64* __restrict__ best, double* __restrict__ wsum,
                            int* __restrict__ ncomp, u32* __restrict__ ticket) {
    const int wave = threadIdx.x >> 6;
    const int lane = threadIdx.x & 63;
    const int row = blockIdx.x * 4 + wave;
    const float2 v = *reinterpret_cast<const float2*>(x + (size_t)row * DIM + lane * 2);
    *reinterpret_cast<ushort2*>(xb + (size_t)row * DIM + lane * 2) =
        make_ushort2(f32_to_bf16(v.x), f32_to_bf16(v.y));
    float s = v.x * v.x + v.y * v.y;
    #pragma unroll
    for (int off = 32; off; off >>= 1) s += __shfl_xor(s, off);
    if (lane == 0) sq[row] = s;

    const int gtid = blockIdx.x * 256 + threadIdx.x;
    if (gtid < N) { comp[gtid] = (u16)gtid; best[gtid] = MAXKEY; }
    if (gtid == 0) { *wsum = 0.0; *ncomp = N; *ticket = 0u; }
}

// ---- K2: D = bf16(sqrt(max(sq_i+sq_j-2*xi.xj, eps))) via MFMA ----
// 64x64 tile / 256-thread block, triangular grid (by<=bx), 9 KB LDS -> 8 blk/CU.
// Mirror tile written from the LDS transpose -> D bitwise symmetric (required
// by the Boruvka hook 2-cycle invariant). [round-5 verified: absmax 0.0]
__global__ __launch_bounds__(256) void dist_mfma_kernel(const u16* __restrict__ xb,
                                                        const float* __restrict__ sq,
                                                        u16* __restrict__ Dm) {
    const int bx = blockIdx.x, by = blockIdx.y;
    if (by > bx) return;
    const int gi0 = by * 64, gj0 = bx * 64;
    const int tid = threadIdx.x;
    const int w = tid >> 6, l = tid & 63;
    const int lr = l & 15, lk = l >> 4;

    __shared__ u16 ldsT[64][72];  // [col][row], pad 72: 8B align + bank spread

    f32x4 acc[4] = {};
    const u16* arow = xb + (size_t)(gi0 + w * 16 + lr) * DIM + lk * 8;
    const u16* brow = xb + (size_t)(gj0 + lr) * DIM + lk * 8;
    #pragma unroll
    for (int ks = 0; ks < 4; ++ks) {
        const short8 a = *reinterpret_cast<const short8*>(arow + ks * 32);
        #pragma unroll
        for (int nj = 0; nj < 4; ++nj) {
            const short8 b = *reinterpret_cast<const short8*>(brow + (size_t)nj * 16 * DIM + ks * 32);
            acc[nj] = __builtin_amdgcn_mfma_f32_16x16x32_bf16(a, b, acc[nj], 0, 0, 0);
        }
    }

    // epilogue: C/D layout col=lane&15, row=(lane>>4)*4+reg [m89-verified]
    const int ri0 = w * 16 + lk * 4;
    #pragma unroll
    for (int nj = 0; nj < 4; ++nj) {
        const int cj = nj * 16 + lr;
        const float sj = sq[gj0 + cj];
        u64 pack = 0;
        #pragma unroll
        for (int r = 0; r < 4; ++r) {
            const float si = sq[gi0 + ri0 + r];
            const float d = sqrtf(fmaxf(si + sj - 2.0f * acc[nj][r], EPSQ));
            const u16 bits = f32_to_bf16(d);
            Dm[(size_t)(gi0 + ri0 + r) * N + gj0 + cj] = bits;
            pack |= (u64)bits << (16 * r);
        }
        *reinterpret_cast<u64*>(&ldsT[cj][ri0]) = pack;  // 4 contiguous rows: one b64
    }

    if (by == bx) return;  // diagonal tile symmetric by itself (uniform exit)
    __syncthreads();
    const int row = tid >> 2, seg = tid & 3;
    const u16* src = &ldsT[row][seg * 16];
    u16* dst = Dm + (size_t)(gj0 + row) * N + gi0 + seg * 16;
    *reinterpret_cast<uint4*>(dst) = *reinterpret_cast<const uint4*>(src);
    *reinterpret_cast<uint4*>(dst + 8) = *reinterpret_cast<const uint4*>(src + 8);
}

// ---- K3: one Boruvka ROUND per dispatch: all blocks scan, LAST block merges ----
// Cross-block comms inside a dispatch: best[] via device atomicMin (+ release:
// syncthreads drains vmcnt before the ticket), ticket via atomicAdd, reader-side
// __threadfence() acquire in the merging block. comp/ncomp/wsum cross rounds via
// dispatch-boundary coherence (the round-5-verified mechanism).
__global__ __launch_bounds__(RTHREADS) void boruvka_round_kernel(
        const u16* __restrict__ Dm, u16* __restrict__ comp, u64* __restrict__ best,
        double* __restrict__ wsum, int* __restrict__ ncomp, u32* __restrict__ ticket,
        float* __restrict__ out, int write_out) {
    __shared__ int parent[N];         // 16 KB (merging block only)
    __shared__ double red[RTHREADS];
    __shared__ int redi[RTHREADS];
    __shared__ int amLast;
    const int tid = threadIdx.x, bid = blockIdx.x;
    const int wave = tid >> 6, lane = tid & 63;
    const int converged = (*ncomp == 1);

    if (!converged) {
        // ---- scan: 2 rows/wave; row-local key (dbits<<12)|j is order-isomorphic
        // to the canonical key within a row; winner re-packed with canonical
        // edge id for the global atomicMin (global total order -> 2-cycles only).
        #pragma unroll
        for (int rr = 0; rr < 2; ++rr) {
            const int i = bid * 8 + wave * 2 + rr;
            const u16 ci = comp[i];
            const u16* row = Dm + (size_t)i * N;
            u32 m = 0xFFFFFFFFu;
            #pragma unroll
            for (int k = 0; k < 8; ++k) {
                const int j0 = k * 512 + lane * 8;
                const us8 dv = *reinterpret_cast<const us8*>(row + j0);
                const us8 cv = *reinterpret_cast<const us8*>(comp + j0);
                #pragma unroll
                for (int e = 0; e < 8; ++e) {
                    const u32 key = ((u32)dv[e] << 12) | (u32)(j0 + e);
                    if (cv[e] != ci && key < m) m = key;  // diagonal filtered by cv==ci
                }
            }
            #pragma unroll
            for (int off = 32; off; off >>= 1) {
                const u32 o = __shfl_xor(m, off);
                m = o < m ? o : m;
            }
            if (lane == 0 && m != 0xFFFFFFFFu) {
                const int j = (int)(m & 0xFFFu);
                const u32 d = m >> 12;
                const int lo = i < j ? i : j;
                const int hi = i < j ? j : i;
                atomicMin(&best[ci], ((u64)d << 24) | (u64)((lo << 12) | hi));
            }
        }
    }

    // ---- ticket: the block drawing the last ticket performs the merge ----
    __syncthreads();  // drains this block's atomicMins (vmcnt(0) before s_barrier)
    if (tid == 0) amLast = (atomicAdd(ticket, 1u) == RBLOCKS - 1u);
    __syncthreads();
    if (!amLast) return;
    __threadfence();  // acquire: invalidate stale lines before reading best[]

    if (converged) {
        if (tid == 0) {
            if (write_out) out[0] = (float)(WEIGHT * (*wsum) / (double)(N - 1));
            *ticket = 0u;
        }
        return;
    }

    // ---- merge (identical deterministic logic to the round-5 merge kernel) ----
    u64 b[QPT];
    #pragma unroll
    for (int q = 0; q < QPT; ++q) {  // hook
        const int c = tid + q * RTHREADS;
        b[q] = best[c];
        int p = c;
        if (b[q] != MAXKEY) {
            const int id = (int)(b[q] & 0xFFFFFFu);
            const int a = id >> 12, e = id & 0xFFF;
            const int ca = comp[a], ce = comp[e];
            p = (ca == c) ? ce : ca;
        }
        parent[c] = p;
    }
    __syncthreads();
    int np[QPT];
    #pragma unroll
    for (int q = 0; q < QPT; ++q) {  // 2-cycle break (read pass)
        const int c = tid + q * RTHREADS;
        const int p = parent[c];
        np[q] = (p != c && parent[p] == c && c < p) ? c : p;
    }
    __syncthreads();
    double myw = 0.0;
    #pragma unroll
    for (int q = 0; q < QPT; ++q) {  // write pass + weight + best reset
        const int c = tid + q * RTHREADS;
        parent[c] = np[q];
        if (np[q] != c)
            myw += (double)__uint_as_float((unsigned)((b[q] >> 24) & 0xFFFFu) << 16);
        best[c] = MAXKEY;
    }
    red[tid] = myw;
    __syncthreads();
    #pragma unroll
    for (int s = RTHREADS / 2; s; s >>= 1) {  // deterministic fixed-order sum
        if (tid < s) red[tid] += red[tid + s];
        __syncthreads();
    }
    for (int it = 0; it < 12; ++it) {  // pointer jumping covers depth 4096
        #pragma unroll
        for (int q = 0; q < QPT; ++q) {
            const int c = tid + q * RTHREADS;
            np[q] = parent[parent[c]];
        }
        __syncthreads();
        #pragma unroll
        for (int q = 0; q < QPT; ++q) parent[tid + q * RTHREADS] = np[q];
        __syncthreads();
    }
    int rc = 0;
    #pragma unroll
    for (int q = 0; q < QPT; ++q) {  // comp update (own-index RMW) + root count
        const int i2 = tid + q * RTHREADS;
        rc += (parent[i2] == i2);
        comp[i2] = (u16)parent[comp[i2]];
    }
    redi[tid] = rc;
    __syncthreads();
    #pragma unroll
    for (int s = RTHREADS / 2; s; s >>= 1) {
        if (tid < s) redi[tid] += redi[tid + s];
        __syncthreads();
    }
    if (tid == 0) {
        const double w = *wsum + red[0];
        *wsum = w;
        *ncomp = redi[0];
        *ticket = 0u;  // re-arm for the next round's dispatch
        if (write_out) out[0] = (float)(WEIGHT * w / (double)(N - 1));
    }
}

extern "C" void kernel_launch(void* const* d_in, const int* in_sizes, int n_in,
                              void* d_out, int out_size, void* d_ws, size_t ws_size,
                              hipStream_t stream) {
    const float* x = (const float*)d_in[0];
    char* ws = (char*)d_ws;
    u16* Dm      = (u16*)ws;                                  // 32 MiB
    u16* xb      = (u16*)(ws + 33554432);                     // 1 MiB
    float* sq    = (float*)(ws + 34603008);                   // 16 KiB
    u16* comp    = (u16*)(ws + 34619392);                     // 8 KiB
    u64* best    = (u64*)(ws + 34627584);                     // 32 KiB
    double* wsum = (double*)(ws + 34660352);                  // 8 B
    int* ncomp   = (int*)(ws + 34660360);                     // 4 B
    u32* ticket  = (u32*)(ws + 34660364);                     // 4 B
    float* out = (float*)d_out;

    prep_kernel<<<N / 4, 256, 0, stream>>>(x, xb, sq, comp, best, wsum, ncomp, ticket);
    dim3 grd(64, 64);
    dist_mfma_kernel<<<grd, 256, 0, stream>>>(xb, sq, Dm);
    for (int r = 0; r < 12; ++r) {
        boruvka_round_kernel<<<RBLOCKS, RTHREADS, 0, stream>>>(
            Dm, comp, best, wsum, ncomp, ticket, out, r == 11 ? 1 : 0);
    }
}

// Round 12
// 364.008 us; speedup vs baseline: 1.1216x; 1.1216x over previous
//
#include <hip/hip_runtime.h>
#include <hip/hip_bf16.h>
#include <cstdint>

#define N 4096
#define DIM 128
#define WEIGHT 0.01f
#define EPSQ 1e-12f
#define MAXKEY 0xFFFFFFFFFFFFFFFFull

#define RBLOCKS 256
#define RTHREADS 1024
#define QPT (N / RTHREADS)  // 4 components per thread in merge (round-5-proven)

typedef unsigned long long u64;
typedef unsigned int u32;
typedef unsigned short u16;
typedef short short8 __attribute__((ext_vector_type(8)));
typedef u16 us8 __attribute__((ext_vector_type(8)));
typedef float f32x4 __attribute__((ext_vector_type(4)));

__device__ __forceinline__ u16 f32_to_bf16(float f) {
    const unsigned u = __float_as_uint(f);
    return (u16)((u + 0x7FFFu + ((u >> 16) & 1u)) >> 16);  // round-to-nearest-even
}

// ---- K1: fused prep: xb = bf16(x), sq = ||x_i||^2, + Boruvka state init ----
__global__ void prep_kernel(const float* __restrict__ x, u16* __restrict__ xb,
                            float* __restrict__ sq, u16* __restrict__ comp,
                            u64* __restrict__ best, double* __restrict__ wsum,
                            int* __restrict__ ncomp, u32* __restrict__ ticket) {
    const int wave = threadIdx.x >> 6;
    const int lane = threadIdx.x & 63;
    const int row = blockIdx.x * 4 + wave;
    const float2 v = *reinterpret_cast<const float2*>(x + (size_t)row * DIM + lane * 2);
    *reinterpret_cast<ushort2*>(xb + (size_t)row * DIM + lane * 2) =
        make_ushort2(f32_to_bf16(v.x), f32_to_bf16(v.y));
    float s = v.x * v.x + v.y * v.y;
    #pragma unroll
    for (int off = 32; off; off >>= 1) s += __shfl_xor(s, off);
    if (lane == 0) sq[row] = s;

    const int gtid = blockIdx.x * 256 + threadIdx.x;
    if (gtid < N) { comp[gtid] = (u16)gtid; best[gtid] = MAXKEY; }
    if (gtid == 0) { *wsum = 0.0; *ncomp = N; *ticket = 0u; }
}

// ---- K2: D = bf16(sqrt(max(sq_i+sq_j-2*xi.xj, eps))) via MFMA ----
// 64x64 tile / 256-thread block, triangular grid (by<=bx), 9 KB LDS -> 8 blk/CU.
// Mirror tile written from the LDS transpose -> D bitwise symmetric (required
// by the Boruvka hook 2-cycle invariant). [round-5 verified: absmax 0.0]
__global__ __launch_bounds__(256) void dist_mfma_kernel(const u16* __restrict__ xb,
                                                        const float* __restrict__ sq,
                                                        u16* __restrict__ Dm) {
    const int bx = blockIdx.x, by = blockIdx.y;
    if (by > bx) return;
    const int gi0 = by * 64, gj0 = bx * 64;
    const int tid = threadIdx.x;
    const int w = tid >> 6, l = tid & 63;
    const int lr = l & 15, lk = l >> 4;

    __shared__ u16 ldsT[64][72];  // [col][row], pad 72: 8B align + bank spread

    f32x4 acc[4] = {};
    const u16* arow = xb + (size_t)(gi0 + w * 16 + lr) * DIM + lk * 8;
    const u16* brow = xb + (size_t)(gj0 + lr) * DIM + lk * 8;
    #pragma unroll
    for (int ks = 0; ks < 4; ++ks) {
        const short8 a = *reinterpret_cast<const short8*>(arow + ks * 32);
        #pragma unroll
        for (int nj = 0; nj < 4; ++nj) {
            const short8 b = *reinterpret_cast<const short8*>(brow + (size_t)nj * 16 * DIM + ks * 32);
            acc[nj] = __builtin_amdgcn_mfma_f32_16x16x32_bf16(a, b, acc[nj], 0, 0, 0);
        }
    }

    // epilogue: C/D layout col=lane&15, row=(lane>>4)*4+reg [m89-verified]
    const int ri0 = w * 16 + lk * 4;
    #pragma unroll
    for (int nj = 0; nj < 4; ++nj) {
        const int cj = nj * 16 + lr;
        const float sj = sq[gj0 + cj];
        u64 pack = 0;
        #pragma unroll
        for (int r = 0; r < 4; ++r) {
            const float si = sq[gi0 + ri0 + r];
            const float d = sqrtf(fmaxf(si + sj - 2.0f * acc[nj][r], EPSQ));
            const u16 bits = f32_to_bf16(d);
            Dm[(size_t)(gi0 + ri0 + r) * N + gj0 + cj] = bits;
            pack |= (u64)bits << (16 * r);
        }
        *reinterpret_cast<u64*>(&ldsT[cj][ri0]) = pack;  // 4 contiguous rows: one b64
    }

    if (by == bx) return;  // diagonal tile symmetric by itself (uniform exit)
    __syncthreads();
    const int row = tid >> 2, seg = tid & 3;
    const u16* src = &ldsT[row][seg * 16];
    u16* dst = Dm + (size_t)(gj0 + row) * N + gi0 + seg * 16;
    *reinterpret_cast<uint4*>(dst) = *reinterpret_cast<const uint4*>(src);
    *reinterpret_cast<uint4*>(dst + 8) = *reinterpret_cast<const uint4*>(src + 8);
}

// ---- K3: one Boruvka ROUND per dispatch: all blocks scan, LAST block merges ----
// Round-10 post-mortem: 512blk x 256thr gave a 256-thread merge (4x serial LDS
// chains, 40 us single-block tail -> 12.5% avg occupancy) and a 2-waves/SIMD
// scan (~300 GB/s, latency-bound). This round: 256blk x 1024thr -> 1 row/wave
// scan (4096 waves) with ALL 16 loads issued before compute, and the
// round-5-proven 1024-thread QPT=4 merge. Sync structure unchanged (verified).
__global__ __launch_bounds__(RTHREADS, 4) void boruvka_round_kernel(
        const u16* __restrict__ Dm, u16* __restrict__ comp, u64* __restrict__ best,
        double* __restrict__ wsum, int* __restrict__ ncomp, u32* __restrict__ ticket,
        float* __restrict__ out, int write_out) {
    __shared__ int parent[N];         // 16 KB (merging block only)
    __shared__ double red[RTHREADS];  // 8 KB
    __shared__ int redi[RTHREADS];    // 4 KB
    __shared__ int amLast;
    const int tid = threadIdx.x, bid = blockIdx.x;
    const int wave = tid >> 6, lane = tid & 63;
    const int converged = (*ncomp == 1);

    if (!converged) {
        // ---- scan: 1 row/wave; issue all 16 loads, then the select chain.
        // Row-local key (dbits<<12)|j is order-isomorphic to the canonical key
        // within a row; winner re-packed with canonical edge id for atomicMin.
        const int i = bid * 16 + wave;
        const u16 ci = comp[i];
        const u16* row = Dm + (size_t)i * N;
        us8 dv[8], cv[8];
        #pragma unroll
        for (int k = 0; k < 8; ++k) {
            const int j0 = k * 512 + lane * 8;
            dv[k] = *reinterpret_cast<const us8*>(row + j0);
            cv[k] = *reinterpret_cast<const us8*>(comp + j0);
        }
        u32 m = 0xFFFFFFFFu;
        #pragma unroll
        for (int k = 0; k < 8; ++k) {
            const int j0 = k * 512 + lane * 8;
            #pragma unroll
            for (int e = 0; e < 8; ++e) {
                const u32 key = ((u32)dv[k][e] << 12) | (u32)(j0 + e);
                if (cv[k][e] != ci && key < m) m = key;  // diagonal filtered by cv==ci
            }
        }
        #pragma unroll
        for (int off = 32; off; off >>= 1) {
            const u32 o = __shfl_xor(m, off);
            m = o < m ? o : m;
        }
        if (lane == 0 && m != 0xFFFFFFFFu) {
            const int j = (int)(m & 0xFFFu);
            const u32 d = m >> 12;
            const int lo = i < j ? i : j;
            const int hi = i < j ? j : i;
            atomicMin(&best[ci], ((u64)d << 24) | (u64)((lo << 12) | hi));
        }
    }

    // ---- ticket: the block drawing the last ticket performs the merge ----
    __syncthreads();  // drains this block's atomicMins (vmcnt(0) before s_barrier)
    if (tid == 0) amLast = (atomicAdd(ticket, 1u) == RBLOCKS - 1u);
    __syncthreads();
    if (!amLast) return;
    __threadfence();  // acquire: invalidate stale lines before reading best[]

    if (converged) {
        if (tid == 0) {
            if (write_out) out[0] = (float)(WEIGHT * (*wsum) / (double)(N - 1));
            *ticket = 0u;
        }
        return;
    }

    // ---- merge (identical deterministic logic to the round-5 merge kernel) ----
    u64 b[QPT];
    #pragma unroll
    for (int q = 0; q < QPT; ++q) {  // hook
        const int c = tid + q * RTHREADS;
        b[q] = best[c];
        int p = c;
        if (b[q] != MAXKEY) {
            const int id = (int)(b[q] & 0xFFFFFFu);
            const int a = id >> 12, e = id & 0xFFF;
            const int ca = comp[a], ce = comp[e];
            p = (ca == c) ? ce : ca;
        }
        parent[c] = p;
    }
    __syncthreads();
    int np[QPT];
    #pragma unroll
    for (int q = 0; q < QPT; ++q) {  // 2-cycle break (read pass)
        const int c = tid + q * RTHREADS;
        const int p = parent[c];
        np[q] = (p != c && parent[p] == c && c < p) ? c : p;
    }
    __syncthreads();
    double myw = 0.0;
    #pragma unroll
    for (int q = 0; q < QPT; ++q) {  // write pass + weight + best reset
        const int c = tid + q * RTHREADS;
        parent[c] = np[q];
        if (np[q] != c)
            myw += (double)__uint_as_float((unsigned)((b[q] >> 24) & 0xFFFFu) << 16);
        best[c] = MAXKEY;
    }
    red[tid] = myw;
    __syncthreads();
    #pragma unroll
    for (int s = RTHREADS / 2; s; s >>= 1) {  // deterministic fixed-order sum
        if (tid < s) red[tid] += red[tid + s];
        __syncthreads();
    }
    for (int it = 0; it < 12; ++it) {  // pointer jumping covers depth 4096
        #pragma unroll
        for (int q = 0; q < QPT; ++q) {
            const int c = tid + q * RTHREADS;
            np[q] = parent[parent[c]];
        }
        __syncthreads();
        #pragma unroll
        for (int q = 0; q < QPT; ++q) parent[tid + q * RTHREADS] = np[q];
        __syncthreads();
    }
    int rc = 0;
    #pragma unroll
    for (int q = 0; q < QPT; ++q) {  // comp update (own-index RMW) + root count
        const int i2 = tid + q * RTHREADS;
        rc += (parent[i2] == i2);
        comp[i2] = (u16)parent[comp[i2]];
    }
    redi[tid] = rc;
    __syncthreads();
    #pragma unroll
    for (int s = RTHREADS / 2; s; s >>= 1) {
        if (tid < s) redi[tid] += redi[tid + s];
        __syncthreads();
    }
    if (tid == 0) {
        const double w = *wsum + red[0];
        *wsum = w;
        *ncomp = redi[0];
        *ticket = 0u;  // re-arm for the next round's dispatch
        if (write_out) out[0] = (float)(WEIGHT * w / (double)(N - 1));
    }
}

extern "C" void kernel_launch(void* const* d_in, const int* in_sizes, int n_in,
                              void* d_out, int out_size, void* d_ws, size_t ws_size,
                              hipStream_t stream) {
    const float* x = (const float*)d_in[0];
    char* ws = (char*)d_ws;
    u16* Dm      = (u16*)ws;                                  // 32 MiB
    u16* xb      = (u16*)(ws + 33554432);                     // 1 MiB
    float* sq    = (float*)(ws + 34603008);                   // 16 KiB
    u16* comp    = (u16*)(ws + 34619392);                     // 8 KiB
    u64* best    = (u64*)(ws + 34627584);                     // 32 KiB
    double* wsum = (double*)(ws + 34660352);                  // 8 B
    int* ncomp   = (int*)(ws + 34660360);                     // 4 B
    u32* ticket  = (u32*)(ws + 34660364);                     // 4 B
    float* out = (float*)d_out;

    prep_kernel<<<N / 4, 256, 0, stream>>>(x, xb, sq, comp, best, wsum, ncomp, ticket);
    dim3 grd(64, 64);
    dist_mfma_kernel<<<grd, 256, 0, stream>>>(xb, sq, Dm);
    for (int r = 0; r < 12; ++r) {
        boruvka_round_kernel<<<RBLOCKS, RTHREADS, 0, stream>>>(
            Dm, comp, best, wsum, ncomp, ticket, out, r == 11 ? 1 : 0);
    }
}

// Round 14
// 265.484 us; speedup vs baseline: 1.5378x; 1.3711x over previous
//
#include <hip/hip_runtime.h>
#include <hip/hip_bf16.h>
#include <cstdint>

#define N 4096
#define DIM 128
#define WEIGHT 0.01f
#define EPSQ 1e-12f

#define RBLOCKS 256
#define RTHREADS 1024
#define QPT 4          // components per thread in replay (4096/1024)
#define NROUNDS 12     // scans r=0..11; dispatch 12 = final merge + out

typedef unsigned long long u64;
typedef unsigned int u32;
typedef unsigned short u16;
typedef short short8 __attribute__((ext_vector_type(8)));
typedef u16 us8 __attribute__((ext_vector_type(8)));
typedef float f32x4 __attribute__((ext_vector_type(4)));

__device__ __forceinline__ u16 f32_to_bf16(float f) {
    const unsigned u = __float_as_uint(f);
    return (u16)((u + 0x7FFFu + ((u >> 16) & 1u)) >> 16);  // round-to-nearest-even
}

// ---- K1: fused prep: xb = bf16(x), sq = ||x_i||^2, + Boruvka state init ----
__global__ void prep_kernel(const float* __restrict__ x, u16* __restrict__ xb,
                            float* __restrict__ sq, u16* __restrict__ comp,
                            u64* __restrict__ best, double* __restrict__ wsum) {
    const int wave = threadIdx.x >> 6;
    const int lane = threadIdx.x & 63;
    const int row = blockIdx.x * 4 + wave;
    const float2 v = *reinterpret_cast<const float2*>(x + (size_t)row * DIM + lane * 2);
    *reinterpret_cast<ushort2*>(xb + (size_t)row * DIM + lane * 2) =
        make_ushort2(f32_to_bf16(v.x), f32_to_bf16(v.y));
    float s = v.x * v.x + v.y * v.y;
    #pragma unroll
    for (int off = 32; off; off >>= 1) s += __shfl_xor(s, off);
    if (lane == 0) sq[row] = s;

    const int gtid = blockIdx.x * 256 + threadIdx.x;
    if (gtid < N) { comp[gtid] = (u16)gtid; best[gtid] = ~0ull; }  // version 0xFF = stale
    if (gtid == 0) *wsum = 0.0;
}

// ---- K2: D = bf16(sqrt(max(sq_i+sq_j-2*xi.xj, eps))) via MFMA ----
// 64x64 tile / 256-thread block, triangular grid (by<=bx), 9 KB LDS.
// Mirror tile written from the LDS transpose -> D bitwise symmetric (required
// by the Boruvka hook 2-cycle invariant). [round-5 verified: absmax 0.0]
__global__ __launch_bounds__(256) void dist_mfma_kernel(const u16* __restrict__ xb,
                                                        const float* __restrict__ sq,
                                                        u16* __restrict__ Dm) {
    const int bx = blockIdx.x, by = blockIdx.y;
    if (by > bx) return;
    const int gi0 = by * 64, gj0 = bx * 64;
    const int tid = threadIdx.x;
    const int w = tid >> 6, l = tid & 63;
    const int lr = l & 15, lk = l >> 4;

    __shared__ u16 ldsT[64][72];

    f32x4 acc[4] = {};
    const u16* arow = xb + (size_t)(gi0 + w * 16 + lr) * DIM + lk * 8;
    const u16* brow = xb + (size_t)(gj0 + lr) * DIM + lk * 8;
    #pragma unroll
    for (int ks = 0; ks < 4; ++ks) {
        const short8 a = *reinterpret_cast<const short8*>(arow + ks * 32);
        #pragma unroll
        for (int nj = 0; nj < 4; ++nj) {
            const short8 b = *reinterpret_cast<const short8*>(brow + (size_t)nj * 16 * DIM + ks * 32);
            acc[nj] = __builtin_amdgcn_mfma_f32_16x16x32_bf16(a, b, acc[nj], 0, 0, 0);
        }
    }

    // epilogue: C/D layout col=lane&15, row=(lane>>4)*4+reg [m89-verified]
    const int ri0 = w * 16 + lk * 4;
    #pragma unroll
    for (int nj = 0; nj < 4; ++nj) {
        const int cj = nj * 16 + lr;
        const float sj = sq[gj0 + cj];
        u64 pack = 0;
        #pragma unroll
        for (int r = 0; r < 4; ++r) {
            const float si = sq[gi0 + ri0 + r];
            const float d = sqrtf(fmaxf(si + sj - 2.0f * acc[nj][r], EPSQ));
            const u16 bits = f32_to_bf16(d);
            Dm[(size_t)(gi0 + ri0 + r) * N + gj0 + cj] = bits;
            pack |= (u64)bits << (16 * r);
        }
        *reinterpret_cast<u64*>(&ldsT[cj][ri0]) = pack;
    }

    if (by == bx) return;
    __syncthreads();
    const int row = tid >> 2, seg = tid & 3;
    const u16* src = &ldsT[row][seg * 16];
    u16* dst = Dm + (size_t)(gj0 + row) * N + gi0 + seg * 16;
    *reinterpret_cast<uint4*>(dst) = *reinterpret_cast<const uint4*>(src);
    *reinterpret_cast<uint4*>(dst + 8) = *reinterpret_cast<const uint4*>(src + 8);
}

// ---- K3: Boruvka round r: EVERY block redundantly replays the round-(r-1)
// merge from best[]+comp[] (pure deterministic function -> identical in all
// blocks; no ticket / single-block tail / threadfence), then scans its 16 rows
// with comp in LDS. Versioned atomicMin keys ((0xFE-r)<<56): newer rounds
// always win -> no best[] reset, no write/read race. live[]-based component
// count fixes the never-firing early exit (dead slots counted as roots before).
__global__ __launch_bounds__(RTHREADS) void boruvka_round_kernel(
        const u16* __restrict__ Dm, u16* __restrict__ comp, u64* __restrict__ best,
        double* __restrict__ wsum, float* __restrict__ out, int r) {
    __shared__ u16 comp_lds[N];        // 8 KB  row -> component
    __shared__ u16 parent[N];          // 8 KB
    __shared__ unsigned char live[N];  // 4 KB
    __shared__ double red[RTHREADS];   // 8 KB
    __shared__ int redi[RTHREADS];     // 4 KB
    const int tid = threadIdx.x, bid = blockIdx.x;
    const int wave = tid >> 6, lane = tid & 63;

    // comp (global, state of round r-1) -> LDS
    *reinterpret_cast<u64*>(&comp_lds[tid * 4]) =
        *reinterpret_cast<const u64*>(&comp[tid * 4]);
    __syncthreads();

    int rc = N;
    if (r > 0) {
        const unsigned expect = 0xFEu - (unsigned)(r - 1);
        // ---- hook (version-gated) ----
        u64 b[QPT];
        int pv[QPT];
        #pragma unroll
        for (int q = 0; q < QPT; ++q) {
            const int c = tid + q * RTHREADS;
            b[q] = best[c];
            int p = c;
            if ((unsigned)(b[q] >> 56) == expect) {
                const int id = (int)(b[q] & 0xFFFFFFu);
                const int a = id >> 12, e = id & 0xFFF;
                const int ca = comp_lds[a], ce = comp_lds[e];
                p = (ca == c) ? ce : ca;
            }
            pv[q] = p;
            parent[c] = (u16)p;
        }
        __syncthreads();
        // ---- 2-cycle break (read pass / barrier / write pass) ----
        int np[QPT];
        #pragma unroll
        for (int q = 0; q < QPT; ++q) {
            const int c = tid + q * RTHREADS;
            const int p = pv[q];
            np[q] = (p != c && parent[p] == c && c < p) ? c : p;
        }
        __syncthreads();
        double myw = 0.0;
        #pragma unroll
        for (int q = 0; q < QPT; ++q) {
            const int c = tid + q * RTHREADS;
            parent[c] = (u16)np[q];
            if (np[q] != c)
                myw += (double)__uint_as_float(((unsigned)(b[q] >> 24) & 0xFFFFu) << 16);
        }
        red[tid] = myw;
        __syncthreads();
        #pragma unroll
        for (int s = RTHREADS / 2; s; s >>= 1) {  // deterministic fixed-order sum
            if (tid < s) red[tid] += red[tid + s];
            __syncthreads();
        }
        // ---- pointer jumping: 12 iters covers depth 4096 ----
        for (int it = 0; it < 12; ++it) {
            u16 t[QPT];
            #pragma unroll
            for (int q = 0; q < QPT; ++q) {
                const int c = tid + q * RTHREADS;
                t[q] = parent[parent[c]];
            }
            __syncthreads();
            #pragma unroll
            for (int q = 0; q < QPT; ++q) parent[tid + q * RTHREADS] = t[q];
            __syncthreads();
        }
        // ---- comp update (own-slot RMW) + live marking ----
        *reinterpret_cast<u32*>(&live[tid * 4]) = 0u;
        __syncthreads();
        #pragma unroll
        for (int q = 0; q < QPT; ++q) {
            const int i = tid + q * RTHREADS;
            const u16 cn = parent[comp_lds[i]];
            comp_lds[i] = cn;
            live[cn] = 1;  // benign same-value race
        }
        __syncthreads();
        int cnt = 0;
        #pragma unroll
        for (int q = 0; q < QPT; ++q) cnt += live[tid + q * RTHREADS];
        redi[tid] = cnt;
        __syncthreads();
        #pragma unroll
        for (int s = RTHREADS / 2; s; s >>= 1) {
            if (tid < s) redi[tid] += redi[tid + s];
            __syncthreads();
        }
        rc = redi[0];  // true #components (distinct comp values) — all blocks agree

        // persist this block's comp slice; block 0 owns wsum/out
        if (tid < 16) comp[bid * 16 + tid] = comp_lds[bid * 16 + tid];
        if (bid == 0 && tid == 0) {
            *wsum += red[0];
            if (r == NROUNDS)
                out[0] = (float)(WEIGHT * (*wsum) / (double)(N - 1));
        }
    }

    // ---- scan: 1 row/wave; dv batched x8 (32 VGPR), comp test from LDS ----
    if (r < NROUNDS && rc > 1) {
        const int i = bid * 16 + wave;
        const u16 ci = comp_lds[i];
        const u16* row = Dm + (size_t)i * N;
        us8 dv[8];
        #pragma unroll
        for (int k = 0; k < 8; ++k)
            dv[k] = *reinterpret_cast<const us8*>(row + k * 512 + lane * 8);
        u32 m = 0xFFFFFFFFu;
        #pragma unroll
        for (int k = 0; k < 8; ++k) {
            const int j0 = k * 512 + lane * 8;
            const us8 cv = *reinterpret_cast<const us8*>(&comp_lds[j0]);
            #pragma unroll
            for (int e = 0; e < 8; ++e) {
                const u32 key = ((u32)dv[k][e] << 12) | (u32)(j0 + e);
                if (cv[e] != ci && key < m) m = key;  // diagonal filtered by cv==ci
            }
        }
        #pragma unroll
        for (int off = 32; off; off >>= 1) {
            const u32 o = __shfl_xor(m, off);
            m = o < m ? o : m;
        }
        if (lane == 0 && m != 0xFFFFFFFFu) {
            const int j = (int)(m & 0xFFFu);
            const u32 d = m >> 12;
            const int lo = i < j ? i : j;
            const int hi = i < j ? j : i;
            const u64 key = ((u64)(0xFEu - (unsigned)r) << 56) |
                            ((u64)d << 24) | (u64)((lo << 12) | hi);
            atomicMin(&best[ci], key);
        }
    }
}

extern "C" void kernel_launch(void* const* d_in, const int* in_sizes, int n_in,
                              void* d_out, int out_size, void* d_ws, size_t ws_size,
                              hipStream_t stream) {
    const float* x = (const float*)d_in[0];
    char* ws = (char*)d_ws;
    u16* Dm      = (u16*)ws;                                  // 32 MiB
    u16* xb      = (u16*)(ws + 33554432);                     // 1 MiB
    float* sq    = (float*)(ws + 34603008);                   // 16 KiB
    u16* comp    = (u16*)(ws + 34619392);                     // 8 KiB
    u64* best    = (u64*)(ws + 34627584);                     // 32 KiB
    double* wsum = (double*)(ws + 34660352);                  // 8 B
    float* out = (float*)d_out;

    prep_kernel<<<N / 4, 256, 0, stream>>>(x, xb, sq, comp, best, wsum);
    dim3 grd(64, 64);
    dist_mfma_kernel<<<grd, 256, 0, stream>>>(xb, sq, Dm);
    for (int r = 0; r <= NROUNDS; ++r) {
        boruvka_round_kernel<<<RBLOCKS, RTHREADS, 0, stream>>>(
            Dm, comp, best, wsum, out, r);
    }
}